// Round 7
// baseline (141.470 us; speedup 1.0000x reference)
//
#include <hip/hip_runtime.h>
#include <hip/hip_bf16.h>
#include <cstdint>
#include <cstddef>

using bf16 = __hip_bfloat16;
typedef __attribute__((ext_vector_type(8))) short short8v;
typedef __attribute__((ext_vector_type(4))) float f32x4;

static constexpr int BATCH = 32;
static constexpr int CH    = 512;   // C
static constexpr int CIc   = 256;   // inter channels
static constexpr int NSP   = 1024;  // H*W
#define EPSV 1e-5f

__device__ __forceinline__ bf16 f2bf(float f) { return __float2bfloat16(f); }

// async global->LDS, 16B per lane; LDS dest = wave-uniform base + lane*16
__device__ __forceinline__ void gload_lds16(const bf16* g, bf16* l) {
  __builtin_amdgcn_global_load_lds(
      (const __attribute__((address_space(1))) void*)g,
      (__attribute__((address_space(3))) void*)l, 16, 0, 0);
}

// ---------------- weight conversion ----------------
__global__ __launch_bounds__(256) void convert_weights(
    const float* __restrict__ wg, const float* __restrict__ wph, const float* __restrict__ wth,
    const float* __restrict__ bg, const float* __restrict__ bph, const float* __restrict__ bth,
    const float* __restrict__ wW,
    bf16* __restrict__ wcat, bf16* __restrict__ wWb, float* __restrict__ biascat)
{
  int i = blockIdx.x * 256 + threadIdx.x;
  const int WSZ = CIc * CH; // 131072
  if (i < WSZ) {
    wcat[i]         = f2bf(wg[i]);
    wcat[WSZ + i]   = f2bf(wph[i]);
    wcat[2*WSZ + i] = f2bf(wth[i]);
    wWb[i]          = f2bf(wW[i]);
  }
  if (i < CIc) {
    biascat[i]        = bg[i];
    biascat[CIc + i]  = bph[i];
    biascat[2*CIc + i]= bth[i];
  }
}

// ---------------- x [B,C,N] fp32 -> xt [B,N,C] bf16 ----------------
__global__ __launch_bounds__(256) void transpose_x_kernel(
    const float* __restrict__ x, bf16* __restrict__ xt)
{
  __shared__ bf16 t[32][34];
  int n0 = blockIdx.x * 32, c0 = blockIdx.y * 32, b = blockIdx.z;
  const float* s = x + (size_t)b * CH * NSP;
  bf16* d = xt + (size_t)b * NSP * CH;
  int tx = threadIdx.x & 31, ty = threadIdx.x >> 5;
  #pragma unroll
  for (int i = 0; i < 32; i += 8)
    t[ty + i][tx] = f2bf(s[(size_t)(c0 + ty + i) * NSP + n0 + tx]);
  __syncthreads();
  #pragma unroll
  for (int i = 0; i < 32; i += 8)
    d[(size_t)(n0 + ty + i) * CH + c0 + tx] = t[tx][ty + i];
}

// ============ 256x256 ring-3 pipelined NT GEMM (BK=32, fragment-major LDS) ============
// 512 thr = 8 waves (wr=wv>>2: rows, wc=wv&3: cols), wave tile 128x64.
// LDS: 3 ring slots x (A 16 frags + B 16 frags) x 1KB = 96KB. frag f of slot s:
// rows f*16+(lane&15), k = tile*32 + (lane>>4)*8; slot addr = frag*512 + lane*8
// elements -> reads AND HW staging writes are base+lane*16: lane-linear, conflict-free
// (r6-verified). Staging source per-lane permuted to match (rule #21).
// Schedule per tile t (slot t%3): 8 ds_reads; SA(t+2); lgkm0; 16 MFMA; 4 ds_reads;
// SB(t+2); lgkm0; 16 MFMA; vmcnt(4); s_barrier.  One barrier/tile, counted vmcnt
// (never 0 except tail), stages ride 2 tiles ahead under the MFMAs.
// EPI 1 (K1): rows<512 -> proj bf16 +bias (b=col>>10); m-tile 2 -> thT transposed.
// EPI 2 (K4): fp32 out = acc*(a/N) + ((bW-mu)*a+beta) + x, batch = blockIdx.z.
template<int EPI>
__global__ __launch_bounds__(512, 2) void gemm_nt_256(
    const bf16* __restrict__ A, size_t sA,
    const bf16* __restrict__ Bm, size_t sB,
    void* __restrict__ Cm,
    int K,
    const float* __restrict__ bias,
    bf16* __restrict__ Tt,
    const float* __restrict__ bW, const float* __restrict__ gma,
    const float* __restrict__ bta, const float* __restrict__ mu,
    const float* __restrict__ var,
    const float* __restrict__ xres)
{
  __shared__ bf16 As[3][16 * 512];   // 16KB per slot
  __shared__ bf16 Bs[3][16 * 512];   // 16KB per slot
  const int zb = blockIdx.z;
  const int m0 = blockIdx.y * 256;
  const int n0 = blockIdx.x * 256;
  const bf16* Ab = A  + (size_t)zb * sA;
  const bf16* Bb = Bm + (size_t)zb * sB;
  const int tid  = threadIdx.x;
  const int wv   = tid >> 6, lane = tid & 63;
  const int l16  = lane & 15, g4 = lane >> 4;
  const int wr   = wv >> 2,  wc = wv & 3;

  f32x4 acc[8][4];
  #pragma unroll
  for (int i = 0; i < 8; ++i)
    #pragma unroll
    for (int j = 0; j < 4; ++j)
      acc[i][j] = (f32x4){0.f, 0.f, 0.f, 0.f};

  // Stage A-frags {wv*2, wv*2+1} of tile tt into slot tt%3 (2 gloads/thread).
  auto SA = [&](int tt) {
    int s = tt % 3;
    int kbase = tt * 32 + g4 * 8;
    #pragma unroll
    for (int q = 0; q < 2; ++q) {
      int f = wv * 2 + q;
      gload_lds16(Ab + (size_t)(m0 + f * 16 + l16) * K + kbase, &As[s][f * 512]);
    }
  };
  auto SB = [&](int tt) {
    int s = tt % 3;
    int kbase = tt * 32 + g4 * 8;
    #pragma unroll
    for (int q = 0; q < 2; ++q) {
      int f = wv * 2 + q;
      gload_lds16(Bb + (size_t)(n0 + f * 16 + l16) * K + kbase, &Bs[s][f * 512]);
    }
  };

  const int nt = K >> 5;
  // prologue: tiles 0 and 1 staged; wait for tile 0 only (4 newest may fly)
  SA(0); SB(0); SA(1); SB(1);
  asm volatile("s_waitcnt vmcnt(4)" ::: "memory");
  __builtin_amdgcn_s_barrier();

  for (int t = 0; t < nt; ++t) {
    const int s = t % 3;
    short8v af[4], bfr[4];
    #pragma unroll
    for (int mf = 0; mf < 4; ++mf)
      af[mf] = *(const short8v*)&As[s][(wr * 8 + mf) * 512 + lane * 8];
    #pragma unroll
    for (int nf = 0; nf < 4; ++nf)
      bfr[nf] = *(const short8v*)&Bs[s][(wc * 4 + nf) * 512 + lane * 8];
    if (t + 2 < nt) SA(t + 2);
    asm volatile("s_waitcnt lgkmcnt(0)" ::: "memory");
    __builtin_amdgcn_sched_barrier(0);
    __builtin_amdgcn_s_setprio(1);
    #pragma unroll
    for (int mf = 0; mf < 4; ++mf)
      #pragma unroll
      for (int nf = 0; nf < 4; ++nf)
        acc[mf][nf] = __builtin_amdgcn_mfma_f32_16x16x32_bf16(af[mf], bfr[nf], acc[mf][nf], 0, 0, 0);
    __builtin_amdgcn_s_setprio(0);

    short8v af2[4];
    #pragma unroll
    for (int mf = 0; mf < 4; ++mf)
      af2[mf] = *(const short8v*)&As[s][(wr * 8 + 4 + mf) * 512 + lane * 8];
    if (t + 2 < nt) SB(t + 2);
    asm volatile("s_waitcnt lgkmcnt(0)" ::: "memory");
    __builtin_amdgcn_sched_barrier(0);
    __builtin_amdgcn_s_setprio(1);
    #pragma unroll
    for (int mf = 0; mf < 4; ++mf)
      #pragma unroll
      for (int nf = 0; nf < 4; ++nf)
        acc[4 + mf][nf] = __builtin_amdgcn_mfma_f32_16x16x32_bf16(af2[mf], bfr[nf], acc[4 + mf][nf], 0, 0, 0);
    __builtin_amdgcn_s_setprio(0);

    if (t + 1 < nt) {
      if (t + 2 < nt) asm volatile("s_waitcnt vmcnt(4)" ::: "memory");  // t+1 landed
      else            asm volatile("s_waitcnt vmcnt(0)" ::: "memory");  // tail drain
      __builtin_amdgcn_s_barrier();
    }
  }

  const int colbase = n0 + wc * 64 + l16;
  const int rowb    = wr * 128 + g4 * 4;

  if constexpr (EPI == 2) {
    #pragma unroll
    for (int mf = 0; mf < 8; ++mf) {
      #pragma unroll
      for (int j = 0; j < 4; ++j) {
        int row = m0 + rowb + mf * 16 + j;
        float a  = gma[row] * rsqrtf(var[row] + EPSV);
        float bb = (bW[row] - mu[row]) * a + bta[row];
        float sc = a * (1.f / (float)NSP);
        #pragma unroll
        for (int nf = 0; nf < 4; ++nf) {
          int col = colbase + nf * 16;
          size_t idx = (size_t)zb * (CH * NSP) + (size_t)row * NSP + col;
          ((float*)Cm)[idx] = acc[mf][nf][j] * sc + bb + ((const float*)xres)[idx];
        }
      }
    }
  } else {
    if (m0 < 512) {
      #pragma unroll
      for (int mf = 0; mf < 8; ++mf)
        #pragma unroll
        for (int j = 0; j < 4; ++j) {
          int row = m0 + rowb + mf * 16 + j;
          float badd = bias[row];
          #pragma unroll
          for (int nf = 0; nf < 4; ++nf) {
            int col = colbase + nf * 16;
            int b = col >> 10, n = col & 1023;
            ((bf16*)Cm)[(size_t)b * (CH * NSP) + (size_t)row * NSP + n] = f2bf(acc[mf][nf][j] + badd);
          }
        }
    } else {
      // theta tile: transposed store thT[b][n][ci], 8B packed
      #pragma unroll
      for (int mf = 0; mf < 8; ++mf) {
        int ci0 = rowb + mf * 16;   // 0..255 (m0==512)
        #pragma unroll
        for (int nf = 0; nf < 4; ++nf) {
          int col = colbase + nf * 16;
          int b = col >> 10, n = col & 1023;
          uint64_t pk = 0;
          #pragma unroll
          for (int j = 0; j < 4; ++j) {
            bf16 bv = f2bf(acc[mf][nf][j] + bias[512 + ci0 + j]);
            pk |= (uint64_t)(*(unsigned short*)&bv) << (16 * j);
          }
          *(uint64_t*)(Tt + (size_t)b * (NSP * CIc) + (size_t)n * CIc + ci0) = pk;
        }
      }
    }
  }
}

// ---------------- r3 2-phase 128x128 kernel (small GEMMs K2/K3) ----------------
__global__ __launch_bounds__(256) void gemm_nt_small(
    const bf16* __restrict__ A, size_t sA,
    const bf16* __restrict__ Bm, size_t sB,
    bf16* __restrict__ Cm, size_t sC,
    int N, int K)
{
  __shared__ bf16 As[2][128 * 64];
  __shared__ bf16 Bs[2][128 * 64];
  const int b  = blockIdx.z;
  const int m0 = blockIdx.y * 128;
  const int n0 = blockIdx.x * 128;
  const bf16* Ab = A  + (size_t)b * sA;
  const bf16* Bb = Bm + (size_t)b * sB;
  const int tid  = threadIdx.x;
  const int wv   = tid >> 6, lane = tid & 63;
  const int l16  = lane & 15, g4 = lane >> 4;
  const int wr   = wv >> 1,  wc = wv & 1;

  f32x4 acc[4][4];
  #pragma unroll
  for (int i = 0; i < 4; ++i)
    #pragma unroll
    for (int j = 0; j < 4; ++j)
      acc[i][j] = (f32x4){0.f, 0.f, 0.f, 0.f};

  auto stage = [&](int ks, int p) {
    #pragma unroll
    for (int i = 0; i < 4; ++i) {
      int s = i * 256 + tid;
      int row = s >> 3, ch8 = (s & 7) << 3;
      gload_lds16(Ab + (size_t)(m0 + row) * K + ks + ch8, &As[p][(i * 256 + wv * 64) * 8]);
      gload_lds16(Bb + (size_t)(n0 + row) * K + ks + ch8, &Bs[p][(i * 256 + wv * 64) * 8]);
    }
  };

  const int nt = K >> 6;
  stage(0, 0);
  __syncthreads();
  for (int t = 0; t < nt; ++t) {
    const int cur = t & 1;
    if (t + 1 < nt) stage((t + 1) << 6, cur ^ 1);
    #pragma unroll
    for (int kk = 0; kk < 2; ++kk) {
      short8v af[4], bfv[4];
      #pragma unroll
      for (int mf = 0; mf < 4; ++mf)
        af[mf] = *(const short8v*)&As[cur][(wr * 64 + mf * 16 + l16) * 64 + kk * 32 + g4 * 8];
      #pragma unroll
      for (int nf = 0; nf < 4; ++nf)
        bfv[nf] = *(const short8v*)&Bs[cur][(wc * 64 + nf * 16 + l16) * 64 + kk * 32 + g4 * 8];
      #pragma unroll
      for (int mf = 0; mf < 4; ++mf)
        #pragma unroll
        for (int nf = 0; nf < 4; ++nf)
          acc[mf][nf] = __builtin_amdgcn_mfma_f32_16x16x32_bf16(af[mf], bfv[nf], acc[mf][nf], 0, 0, 0);
    }
    __syncthreads();
  }

  const int colbase = n0 + wc * 64 + l16;
  const int rowbase = m0 + wr * 64 + g4 * 4;
  #pragma unroll
  for (int mf = 0; mf < 4; ++mf)
    #pragma unroll
    for (int j = 0; j < 4; ++j) {
      int row = rowbase + mf * 16 + j;
      #pragma unroll
      for (int nf = 0; nf < 4; ++nf) {
        int col = colbase + nf * 16;
        Cm[(size_t)b * sC + (size_t)row * N + col] = f2bf(acc[mf][nf][j]);
      }
    }
}

extern "C" void kernel_launch(void* const* d_in, const int* in_sizes, int n_in,
                              void* d_out, int out_size, void* d_ws, size_t ws_size,
                              hipStream_t stream)
{
  const float* x    = (const float*)d_in[0];
  const float* w_g  = (const float*)d_in[1];
  const float* b_g  = (const float*)d_in[2];
  const float* w_th = (const float*)d_in[3];
  const float* b_th = (const float*)d_in[4];
  const float* w_ph = (const float*)d_in[5];
  const float* b_ph = (const float*)d_in[6];
  const float* w_W  = (const float*)d_in[7];
  const float* b_W  = (const float*)d_in[8];
  const float* gma  = (const float*)d_in[9];
  const float* bta  = (const float*)d_in[10];
  const float* mu   = (const float*)d_in[11];
  const float* var  = (const float*)d_in[12];
  float* out = (float*)d_out;

  char* ws = (char*)d_ws;
  bf16* proj = (bf16*)(ws + 0);            // [32][512][1024]  g(0-255), phi(256-511)
  bf16* xt   = (bf16*)(ws + 33554432);     // [32][1024][512]
  bf16* thT  = (bf16*)(ws + 67108864);     // [32][1024][256]
  bf16* S    = (bf16*)(ws + 83886080);     // [32][256][256]
  bf16* T    = (bf16*)(ws + 88080384);     // [32][512][256]
  bf16* wcat = (bf16*)(ws + 96468992);     // [768][512]
  bf16* wWb  = (bf16*)(ws + 97255424);     // [512][256]
  float* bcat= (float*)(ws + 97517568);    // [768]

  convert_weights<<<512, 256, 0, stream>>>(w_g, w_ph, w_th, b_g, b_ph, b_th, w_W, wcat, wWb, bcat);
  transpose_x_kernel<<<dim3(32, 16, 32), 256, 0, stream>>>(x, xt);

  // K1: [768 x 32768] = wcat . xt^T, K=512  (batch folded into cols)
  gemm_nt_256<1><<<dim3(128, 3, 1), 512, 0, stream>>>(
      wcat, 0, xt, 0, proj, CH, bcat, thT,
      nullptr, nullptr, nullptr, nullptr, nullptr, nullptr);

  // K2: S = phi . g^T   (M=256, N=256, K=1024) per batch
  gemm_nt_small<<<dim3(2, 2, 32), 256, 0, stream>>>(
      proj + 256 * 1024, (size_t)CH * NSP, proj, (size_t)CH * NSP, S, (size_t)CIc * CIc,
      CIc, NSP);

  // K3: T = wW . S^T    (M=512, N=256, K=256) per batch
  gemm_nt_small<<<dim3(2, 4, 32), 256, 0, stream>>>(
      wWb, 0, S, (size_t)CIc * CIc, T, (size_t)CH * CIc,
      CIc, CIc);

  // K4: out = BN(T . thT^T / N + bW) + x   (M=512, N=1024, K=256) per batch
  gemm_nt_256<2><<<dim3(4, 2, 32), 512, 0, stream>>>(
      T, (size_t)CH * CIc, thT, (size_t)NSP * CIc, out, CIc,
      nullptr, nullptr, b_W, gma, bta, mu, var, x);
}

// Round 8
// 132.121 us; speedup vs baseline: 1.0708x; 1.0708x over previous
//
#include <hip/hip_runtime.h>
#include <hip/hip_bf16.h>
#include <cstdint>
#include <cstddef>

using bf16 = __hip_bfloat16;
typedef __attribute__((ext_vector_type(8))) short short8v;
typedef __attribute__((ext_vector_type(4))) float f32x4;

static constexpr int BATCH = 32;
static constexpr int CH    = 512;   // C
static constexpr int CIc   = 256;   // inter channels
static constexpr int NSP   = 1024;  // H*W
#define EPSV 1e-5f

__device__ __forceinline__ bf16 f2bf(float f) { return __float2bfloat16(f); }

// async global->LDS, 16B per lane; LDS dest = wave-uniform base + lane*16
__device__ __forceinline__ void gload_lds16(const bf16* g, bf16* l) {
  __builtin_amdgcn_global_load_lds(
      (const __attribute__((address_space(1))) void*)g,
      (__attribute__((address_space(3))) void*)l, 16, 0, 0);
}

// ---------------- weight conversion ----------------
__global__ __launch_bounds__(256) void convert_weights(
    const float* __restrict__ wg, const float* __restrict__ wph, const float* __restrict__ wth,
    const float* __restrict__ bg, const float* __restrict__ bph, const float* __restrict__ bth,
    const float* __restrict__ wW,
    bf16* __restrict__ wcat, bf16* __restrict__ wWb, float* __restrict__ biascat)
{
  int i = blockIdx.x * 256 + threadIdx.x;
  const int WSZ = CIc * CH; // 131072
  if (i < WSZ) {
    wcat[i]         = f2bf(wg[i]);
    wcat[WSZ + i]   = f2bf(wph[i]);
    wcat[2*WSZ + i] = f2bf(wth[i]);
    wWb[i]          = f2bf(wW[i]);
  }
  if (i < CIc) {
    biascat[i]        = bg[i];
    biascat[CIc + i]  = bph[i];
    biascat[2*CIc + i]= bth[i];
  }
}

// ---------------- x [B,C,N] fp32 -> xt [B,N,C] bf16 ----------------
__global__ __launch_bounds__(256) void transpose_x_kernel(
    const float* __restrict__ x, bf16* __restrict__ xt)
{
  __shared__ bf16 t[32][34];
  int n0 = blockIdx.x * 32, c0 = blockIdx.y * 32, b = blockIdx.z;
  const float* s = x + (size_t)b * CH * NSP;
  bf16* d = xt + (size_t)b * NSP * CH;
  int tx = threadIdx.x & 31, ty = threadIdx.x >> 5;
  #pragma unroll
  for (int i = 0; i < 32; i += 8)
    t[ty + i][tx] = f2bf(s[(size_t)(c0 + ty + i) * NSP + n0 + tx]);
  __syncthreads();
  #pragma unroll
  for (int i = 0; i < 32; i += 8)
    d[(size_t)(n0 + ty + i) * CH + c0 + tx] = t[tx][ty + i];
}

// ========== 256x128 NT GEMM, BK=32, 512 thr, OCCUPANCY-FIRST (2 blocks/CU) ==========
// 8 waves: wr=wv>>1 (4 row-strips of 64), wc=wv&1 (2 col-strips of 64); acc[4][4]=64
// regs -> with launch_bounds(512,4) total regs <=128 => 16 waves/CU co-resident.
// LDS 48KB: As[2][256*32], Bs[2][128*32], row-major [row][32] with the r5-verified
// free 2-way XOR (slot = oct ^ ((row>>1)&3)) applied to stage SOURCE and read slot
// (rule #21). Staging stays 64B-segment coalesced. Schedule = T3-minimum dbuf:
// issue stage(t+1) -> ds_read(t) -> MFMA -> __syncthreads (cross-block TLP hides drain).
// EPI 1 (K1, flat 768-block grid, XCD-swizzled): m0<512 -> proj bf16 +bias (b=col>>10);
//        m0==512 -> thT transposed 8B-packed store.
// EPI 2 (K4): fp32 out = acc*(a/N) + ((bW-mu)*a+beta) + x, batch = blockIdx.z.
template<int EPI>
__global__ __launch_bounds__(512, 4) void gemm_bt(
    const bf16* __restrict__ A, size_t sA,
    const bf16* __restrict__ Bm, size_t sB,
    void* __restrict__ Cm,
    int K,
    const float* __restrict__ bias,
    bf16* __restrict__ Tt,
    const float* __restrict__ bW, const float* __restrict__ gma,
    const float* __restrict__ bta, const float* __restrict__ mu,
    const float* __restrict__ var,
    const float* __restrict__ xres)
{
  __shared__ bf16 As[2][256 * 32];   // 16KB per buf
  __shared__ bf16 Bs[2][128 * 32];   // 8KB per buf
  int m0, n0, zb;
  if constexpr (EPI == 1) {
    int bidx = blockIdx.x;                       // 768 = 8 XCD chunks x 96
    int wg = (bidx & 7) * 96 + (bidx >> 3);      // bijective (768 % 8 == 0)
    m0 = (wg >> 8) * 256;                        // wg/256 in {0,1,2}
    n0 = (wg & 255) * 128;
    zb = 0;
  } else {
    m0 = blockIdx.y * 256; n0 = blockIdx.x * 128; zb = blockIdx.z;
  }
  const bf16* Ab = A  + (size_t)zb * sA;
  const bf16* Bb = Bm + (size_t)zb * sB;
  const int tid  = threadIdx.x;
  const int wv   = tid >> 6, lane = tid & 63;
  const int l16  = lane & 15, g4 = lane >> 4;
  const int wr   = wv >> 1,  wc = wv & 1;

  f32x4 acc[4][4];
  #pragma unroll
  for (int i = 0; i < 4; ++i)
    #pragma unroll
    for (int j = 0; j < 4; ++j)
      acc[i][j] = (f32x4){0.f, 0.f, 0.f, 0.f};

  // Staging: per thread 2 A-gloads + 1 B-gload per tile. Lane L of frag f covers
  // row f*16 + (L>>2), source k-octet (L&3)^((L>>3)&3) -> LDS slot L (linear dest),
  // i.e. LDS (row, slot s) holds global oct s ^ ((row>>1)&3). 64B-coalesced.
  const int rq  = lane >> 2;
  const int oct = (lane & 3) ^ ((lane >> 3) & 3);
  auto stage = [&](int t, int p) {
    int kb = t * 32 + oct * 8;
    #pragma unroll
    for (int i = 0; i < 2; ++i) {
      int f = wv * 2 + i;
      gload_lds16(Ab + (size_t)(m0 + f * 16 + rq) * K + kb, &As[p][f * 512]);
    }
    gload_lds16(Bb + (size_t)(n0 + wv * 16 + rq) * K + kb, &Bs[p][wv * 512]);
  };

  const int rs = (g4 ^ ((l16 >> 1) & 3)) * 8;   // swizzled read slot (free 2-way)
  const int nt = K >> 5;
  stage(0, 0);
  __syncthreads();
  for (int t = 0; t < nt; ++t) {
    const int cur = t & 1;
    if (t + 1 < nt) stage(t + 1, cur ^ 1);      // in flight under reads+MFMA
    short8v af[4], bfv[4];
    #pragma unroll
    for (int mf = 0; mf < 4; ++mf)
      af[mf] = *(const short8v*)&As[cur][(wr * 64 + mf * 16 + l16) * 32 + rs];
    #pragma unroll
    for (int nf = 0; nf < 4; ++nf)
      bfv[nf] = *(const short8v*)&Bs[cur][(wc * 64 + nf * 16 + l16) * 32 + rs];
    #pragma unroll
    for (int mf = 0; mf < 4; ++mf)
      #pragma unroll
      for (int nf = 0; nf < 4; ++nf)
        acc[mf][nf] = __builtin_amdgcn_mfma_f32_16x16x32_bf16(af[mf], bfv[nf], acc[mf][nf], 0, 0, 0);
    __syncthreads();
  }

  const int colbase = n0 + wc * 64 + l16;
  const int rowb    = wr * 64 + g4 * 4;

  if constexpr (EPI == 2) {
    #pragma unroll
    for (int mf = 0; mf < 4; ++mf) {
      #pragma unroll
      for (int j = 0; j < 4; ++j) {
        int row = m0 + rowb + mf * 16 + j;
        float a  = gma[row] * rsqrtf(var[row] + EPSV);
        float bb = (bW[row] - mu[row]) * a + bta[row];
        float sc = a * (1.f / (float)NSP);
        #pragma unroll
        for (int nf = 0; nf < 4; ++nf) {
          int col = colbase + nf * 16;
          size_t idx = (size_t)zb * (CH * NSP) + (size_t)row * NSP + col;
          ((float*)Cm)[idx] = acc[mf][nf][j] * sc + bb + ((const float*)xres)[idx];
        }
      }
    }
  } else {
    if (m0 < 512) {
      #pragma unroll
      for (int mf = 0; mf < 4; ++mf)
        #pragma unroll
        for (int j = 0; j < 4; ++j) {
          int row = m0 + rowb + mf * 16 + j;
          float badd = bias[row];
          #pragma unroll
          for (int nf = 0; nf < 4; ++nf) {
            int col = colbase + nf * 16;
            int b = col >> 10, n = col & 1023;
            ((bf16*)Cm)[(size_t)b * (CH * NSP) + (size_t)row * NSP + n] = f2bf(acc[mf][nf][j] + badd);
          }
        }
    } else {
      // theta tile: transposed store thT[b][n][ci], 8B packed
      #pragma unroll
      for (int mf = 0; mf < 4; ++mf) {
        int ci0 = rowb + mf * 16;   // 0..255 (m0==512)
        #pragma unroll
        for (int nf = 0; nf < 4; ++nf) {
          int col = colbase + nf * 16;
          int b = col >> 10, n = col & 1023;
          uint64_t pk = 0;
          #pragma unroll
          for (int j = 0; j < 4; ++j) {
            bf16 bv = f2bf(acc[mf][nf][j] + bias[512 + ci0 + j]);
            pk |= (uint64_t)(*(unsigned short*)&bv) << (16 * j);
          }
          *(uint64_t*)(Tt + (size_t)b * (NSP * CIc) + (size_t)n * CIc + ci0) = pk;
        }
      }
    }
  }
}

// ---------------- r3 2-phase 128x128 kernel (small GEMMs K2/K3) ----------------
__global__ __launch_bounds__(256) void gemm_nt_small(
    const bf16* __restrict__ A, size_t sA,
    const bf16* __restrict__ Bm, size_t sB,
    bf16* __restrict__ Cm, size_t sC,
    int N, int K)
{
  __shared__ bf16 As[2][128 * 64];
  __shared__ bf16 Bs[2][128 * 64];
  const int b  = blockIdx.z;
  const int m0 = blockIdx.y * 128;
  const int n0 = blockIdx.x * 128;
  const bf16* Ab = A  + (size_t)b * sA;
  const bf16* Bb = Bm + (size_t)b * sB;
  const int tid  = threadIdx.x;
  const int wv   = tid >> 6, lane = tid & 63;
  const int l16  = lane & 15, g4 = lane >> 4;
  const int wr   = wv >> 1,  wc = wv & 1;

  f32x4 acc[4][4];
  #pragma unroll
  for (int i = 0; i < 4; ++i)
    #pragma unroll
    for (int j = 0; j < 4; ++j)
      acc[i][j] = (f32x4){0.f, 0.f, 0.f, 0.f};

  auto stage = [&](int ks, int p) {
    #pragma unroll
    for (int i = 0; i < 4; ++i) {
      int s = i * 256 + tid;
      int row = s >> 3, ch8 = (s & 7) << 3;
      gload_lds16(Ab + (size_t)(m0 + row) * K + ks + ch8, &As[p][(i * 256 + wv * 64) * 8]);
      gload_lds16(Bb + (size_t)(n0 + row) * K + ks + ch8, &Bs[p][(i * 256 + wv * 64) * 8]);
    }
  };

  const int nt = K >> 6;
  stage(0, 0);
  __syncthreads();
  for (int t = 0; t < nt; ++t) {
    const int cur = t & 1;
    if (t + 1 < nt) stage((t + 1) << 6, cur ^ 1);
    #pragma unroll
    for (int kk = 0; kk < 2; ++kk) {
      short8v af[4], bfv[4];
      #pragma unroll
      for (int mf = 0; mf < 4; ++mf)
        af[mf] = *(const short8v*)&As[cur][(wr * 64 + mf * 16 + l16) * 64 + kk * 32 + g4 * 8];
      #pragma unroll
      for (int nf = 0; nf < 4; ++nf)
        bfv[nf] = *(const short8v*)&Bs[cur][(wc * 64 + nf * 16 + l16) * 64 + kk * 32 + g4 * 8];
      #pragma unroll
      for (int mf = 0; mf < 4; ++mf)
        #pragma unroll
        for (int nf = 0; nf < 4; ++nf)
          acc[mf][nf] = __builtin_amdgcn_mfma_f32_16x16x32_bf16(af[mf], bfv[nf], acc[mf][nf], 0, 0, 0);
    }
    __syncthreads();
  }

  const int colbase = n0 + wc * 64 + l16;
  const int rowbase = m0 + wr * 64 + g4 * 4;
  #pragma unroll
  for (int mf = 0; mf < 4; ++mf)
    #pragma unroll
    for (int j = 0; j < 4; ++j) {
      int row = rowbase + mf * 16 + j;
      #pragma unroll
      for (int nf = 0; nf < 4; ++nf) {
        int col = colbase + nf * 16;
        Cm[(size_t)b * sC + (size_t)row * N + col] = f2bf(acc[mf][nf][j]);
      }
    }
}

extern "C" void kernel_launch(void* const* d_in, const int* in_sizes, int n_in,
                              void* d_out, int out_size, void* d_ws, size_t ws_size,
                              hipStream_t stream)
{
  const float* x    = (const float*)d_in[0];
  const float* w_g  = (const float*)d_in[1];
  const float* b_g  = (const float*)d_in[2];
  const float* w_th = (const float*)d_in[3];
  const float* b_th = (const float*)d_in[4];
  const float* w_ph = (const float*)d_in[5];
  const float* b_ph = (const float*)d_in[6];
  const float* w_W  = (const float*)d_in[7];
  const float* b_W  = (const float*)d_in[8];
  const float* gma  = (const float*)d_in[9];
  const float* bta  = (const float*)d_in[10];
  const float* mu   = (const float*)d_in[11];
  const float* var  = (const float*)d_in[12];
  float* out = (float*)d_out;

  char* ws = (char*)d_ws;
  bf16* proj = (bf16*)(ws + 0);            // [32][512][1024]  g(0-255), phi(256-511)
  bf16* xt   = (bf16*)(ws + 33554432);     // [32][1024][512]
  bf16* thT  = (bf16*)(ws + 67108864);     // [32][1024][256]
  bf16* S    = (bf16*)(ws + 83886080);     // [32][256][256]
  bf16* T    = (bf16*)(ws + 88080384);     // [32][512][256]
  bf16* wcat = (bf16*)(ws + 96468992);     // [768][512]
  bf16* wWb  = (bf16*)(ws + 97255424);     // [512][256]
  float* bcat= (float*)(ws + 97517568);    // [768]

  convert_weights<<<512, 256, 0, stream>>>(w_g, w_ph, w_th, b_g, b_ph, b_th, w_W, wcat, wWb, bcat);
  transpose_x_kernel<<<dim3(32, 16, 32), 256, 0, stream>>>(x, xt);

  // K1: [768 x 32768] = wcat . xt^T, K=512  (batch folded into cols), 768 blocks
  gemm_bt<1><<<dim3(768, 1, 1), 512, 0, stream>>>(
      wcat, 0, xt, 0, proj, CH, bcat, thT,
      nullptr, nullptr, nullptr, nullptr, nullptr, nullptr);

  // K2: S = phi . g^T   (M=256, N=256, K=1024) per batch
  gemm_nt_small<<<dim3(2, 2, 32), 256, 0, stream>>>(
      proj + 256 * 1024, (size_t)CH * NSP, proj, (size_t)CH * NSP, S, (size_t)CIc * CIc,
      CIc, NSP);

  // K3: T = wW . S^T    (M=512, N=256, K=256) per batch
  gemm_nt_small<<<dim3(2, 4, 32), 256, 0, stream>>>(
      wWb, 0, S, (size_t)CIc * CIc, T, (size_t)CH * CIc,
      CIc, CIc);

  // K4: out = BN(T . thT^T / N + bW) + x   (M=512, N=1024, K=256), 512 blocks
  gemm_bt<2><<<dim3(8, 2, 32), 512, 0, stream>>>(
      T, (size_t)CH * CIc, thT, (size_t)NSP * CIc, out, CIc,
      nullptr, nullptr, b_W, gma, bta, mu, var, x);
}